// Round 3
// baseline (637.633 us; speedup 1.0000x reference)
//
#include <hip/hip_runtime.h>

#define NV 2708
#define INC 1433
#define XCOLS 1472        // padded X/W cols (23*64)
#define UDIM 2752         // padded U dims (43*64)
#define PSTR 2728         // pbuf stride in shorts: 1364 words %32=20 -> 2-way max on b128 reads
#define BSTR 2752
#define SLAB ((size_t)(2752*64))   // fp32 partial slab
#define MWPR 88
#define NSP 8             // proj split-K chunks
#define NSU 22            // gemmG/gemmF split-K chunks (2752 = 21*128 + 64)

typedef __attribute__((ext_vector_type(8))) short bf16x8;
typedef __attribute__((ext_vector_type(4))) float f32x4;
typedef __attribute__((ext_vector_type(4))) unsigned short u16x4;

__device__ __forceinline__ unsigned short f2bf(float f){
  union { float f; unsigned int i; } v; v.f = f;
  return (unsigned short)((v.i + 0x7fffu + ((v.i >> 16) & 1u)) >> 16);  // RNE
}

// convert one fp32 row (INC elems, 4B-aligned base) to bf16 with zero pad to
// XCOLS. float2 via parity shift: src+sh is 8B-aligned (sh in {0,1}).
__device__ __forceinline__ void conv_row(const float* __restrict__ src,
                                         unsigned short* __restrict__ dst, int tid){
  const int sh = ((unsigned int)((size_t)src >> 2)) & 1;
  if (tid == 0){ int ce = sh ? 0 : (INC - 1); dst[ce] = f2bf(src[ce]); }
  const float2* s2 = (const float2*)(src + sh);
  for (int c2 = tid; c2 < (INC - 1)/2; c2 += 256){   // 716 pairs
    float2 v = s2[c2];
    int c = sh + c2*2;
    dst[c]     = f2bf(v.x);
    dst[c + 1] = f2bf(v.y);
  }
  for (int c = INC + tid; c < XCOLS; c += 256) dst[c] = 0;
}

// ====== convert_all: one-row blocks; also zeroes the fold counters ==========
__global__ __launch_bounds__(256) void convert_all(
    const float* __restrict__ X, const float* __restrict__ WK,
    const float* __restrict__ WQ, const float* __restrict__ WV,
    const float* __restrict__ U, const int* __restrict__ A,
    unsigned short* __restrict__ Xbf, unsigned short* __restrict__ Wbf,
    unsigned short* __restrict__ Ubf, unsigned int* __restrict__ Abits,
    unsigned int* __restrict__ ctr)
{
  const int bx = blockIdx.x;
  const int tid = threadIdx.x;
  if (bx == 0 && tid < 256) ctr[tid] = 0u;     // fold counters (re-zeroed every run)
  if (bx < 2752){                      // U row (16B-aligned: float4)
    const int row = bx;
    unsigned short* dst = Ubf + (size_t)row*UDIM;
    if (row < NV){
      const float* src = U + (size_t)row*NV;
      for (int c4 = tid; c4 < 688; c4 += 256){
        float4 v = make_float4(0.f,0.f,0.f,0.f);
        if (c4 < 677) v = *(const float4*)(src + c4*4);
        u16x4 h = { f2bf(v.x), f2bf(v.y), f2bf(v.z), f2bf(v.w) };
        *(u16x4*)(dst + c4*4) = h;
      }
    } else {
      u16x4 zz = {0,0,0,0};
      for (int c4 = tid; c4 < 688; c4 += 256) *(u16x4*)(dst + c4*4) = zz;
    }
  } else if (bx < 5504){               // X row (float2 parity trick)
    const int row = bx - 2752;
    unsigned short* dst = Xbf + (size_t)row*XCOLS;
    if (row < NV){
      conv_row(X + (size_t)row*INC, dst, tid);
    } else {
      u16x4 zz = {0,0,0,0};
      for (int c4 = tid; c4 < XCOLS/4; c4 += 256) *(u16x4*)(dst + c4*4) = zz;
    }
  } else if (bx < 5696){               // W row (192 rows)
    const int row = bx - 5504;
    const float* s = (row < 64) ? WK : (row < 128) ? WQ : WV;
    conv_row(s + (size_t)(row & 63)*INC, Wbf + (size_t)row*XCOLS, tid);
  } else {                             // A row -> bitmask (int4, grouped layout)
    const int i = bx - 5696;
    const int lane = tid & 63, wave = tid >> 6;
    const int* arow = A + (size_t)i*NV;
    unsigned int* drow = Abits + (size_t)i*MWPR;
    // word(col): g=col>>8, s=col&255 -> g*8+(s&3)*2+((s>>2)>>5), bit (s>>2)&31
    for (int g = wave; g < 11; g += 4){
      int base = g*256 + lane*4;
      int4 v = make_int4(0,0,0,0);
      if (base < NV) v = *(const int4*)(arow + base);   // base<=2704 -> +3 in bounds
      unsigned long long m0 = __ballot(v.x != 0);
      unsigned long long m1 = __ballot(v.y != 0);
      unsigned long long m2 = __ballot(v.z != 0);
      unsigned long long m3 = __ballot(v.w != 0);
      if (lane < 8){
        unsigned long long mm = (lane < 2) ? m0 : (lane < 4) ? m1 : (lane < 6) ? m2 : m3;
        drow[g*8 + lane] = (lane & 1) ? (unsigned int)(mm >> 32) : (unsigned int)mm;
      }
    }
  }
}

// =============== proj: {K,Q,V} = Xbf @ Wbf^T. grid (43,8,3) =================
// Split-K partials + last-arrival block folds the reduction (GSU pattern).
__global__ __launch_bounds__(256) void proj(
    const unsigned short* __restrict__ Xbf, const unsigned short* __restrict__ Wbf,
    float* __restrict__ part, unsigned int* __restrict__ ctr,
    unsigned short* __restrict__ K16f, unsigned short* __restrict__ QT16,
    unsigned short* __restrict__ VTf)
{
  __shared__ __align__(16) unsigned short At[64*72];
  __shared__ __align__(16) unsigned short Bt[64*72];
  __shared__ unsigned int scnt;
  const int tid = threadIdx.x;
  const int lane = tid & 63, wave = tid >> 6, quad = lane >> 4, lr = lane & 15;
  const int m0 = blockIdx.x * 64;
  const int s  = blockIdx.y, z = blockIdx.z;
  const int kbeg = s * 192, kend = min(kbeg + 192, XCOLS);  // last chunk 128
  const int wm = (wave & 1) * 32, wn = (wave >> 1) * 32;
  const unsigned short* Wz = Wbf + (size_t)z*64*XCOLS;
  const int srow = wave*8 + (lane >> 3), seg = lane & 7;
  f32x4 acc[2][2] = {};

  for (int k0 = kbeg; k0 < kend; k0 += 64){
    #pragma unroll
    for (int e = 0; e < 2; e++){
      int row = e*32 + srow;
      bf16x8 xa = *(const bf16x8*)(Xbf + (size_t)(m0+row)*XCOLS + k0 + seg*8);
      bf16x8 wb = *(const bf16x8*)(Wz  + (size_t)row*XCOLS      + k0 + seg*8);
      *(bf16x8*)&At[row*72 + seg*8] = xa;
      *(bf16x8*)&Bt[row*72 + seg*8] = wb;
    }
    __syncthreads();
    #pragma unroll
    for (int ks = 0; ks < 2; ks++){
      bf16x8 af[2], bv[2];
      #pragma unroll
      for (int t = 0; t < 2; t++){
        af[t] = *(const bf16x8*)&At[(wm + t*16 + lr)*72 + ks*32 + quad*8];
        bv[t] = *(const bf16x8*)&Bt[(wn + t*16 + lr)*72 + ks*32 + quad*8];
      }
      #pragma unroll
      for (int tm = 0; tm < 2; tm++)
        #pragma unroll
        for (int tn = 0; tn < 2; tn++)
          acc[tm][tn] = __builtin_amdgcn_mfma_f32_16x16x32_bf16(af[tm], bv[tn], acc[tm][tn], 0, 0, 0);
    }
    __syncthreads();
  }
  float* dst = part + (size_t)(z*NSP + s) * SLAB;
  #pragma unroll
  for (int tm = 0; tm < 2; tm++)
    #pragma unroll
    for (int tn = 0; tn < 2; tn++)
      #pragma unroll
      for (int e = 0; e < 4; e++)
        dst[(size_t)(m0 + wm + tm*16 + quad*4 + e)*64 + wn + tn*16 + lr] = acc[tm][tn][e];

  // ---- fold: last block for (z,m0) reduces the 8 slabs and writes layouts
  __threadfence();
  __syncthreads();
  if (tid == 0) scnt = atomicAdd(&ctr[z*43 + blockIdx.x], 1u);
  __syncthreads();
  if (scnt == NSP - 1){
    __threadfence();   // acquire
    const float* base = part + (size_t)(z*NSP)*SLAB + (size_t)m0*64;
    for (int idx = tid; idx < 4096; idx += 256){
      int m = m0 + (idx >> 6), c = idx & 63;
      float v = 0.f;
      #pragma unroll
      for (int s2 = 0; s2 < NSP; s2++) v += base[s2*SLAB + idx];
      unsigned short h = (m < NV) ? f2bf(v) : (unsigned short)0;
      if (z == 0){
        if (m < 2720) K16f[((m>>4)*2 + (c>>5))*512 + (m&15)*32 + (c&31)] = h;
      } else if (z == 1){
        QT16[(size_t)c*BSTR + m] = h;
      } else {
        if (m < 2720) VTf[(m>>5)*2048 + c*32 + (m&31)] = h;
      }
    }
  }
}

// =============== gemmG: G = Ubf^T @ Q, split-K + fold(reduce_g). grid (43,22)
__global__ __launch_bounds__(256) void gemmG(
    const unsigned short* __restrict__ Ubf, const unsigned short* __restrict__ QT,
    float* __restrict__ part, unsigned int* __restrict__ ctr,
    const float* __restrict__ lm, unsigned short* __restrict__ G2T)
{
  __shared__ __align__(16) unsigned short At[64*72];
  __shared__ __align__(16) unsigned short Bt[64*72];
  __shared__ unsigned int scnt;
  const int tid = threadIdx.x;
  const int lane = tid & 63, wave = tid >> 6, quad = lane >> 4, lr = lane & 15;
  const int m0 = blockIdx.x * 64;
  const int s  = blockIdx.y;
  const int kbeg = s * 128, kend = min(kbeg + 128, UDIM);   // last chunk 64
  const int wm = (wave & 1) * 32, wn = (wave >> 1) * 32;
  const int bc = tid >> 2, bseg = tid & 3;
  const int ml = (lane & 15)*4, koff = wave*16 + (lane >> 4);
  f32x4 acc[2][2] = {};

  for (int k0 = kbeg; k0 < kend; k0 += 64){
    #pragma unroll
    for (int e = 0; e < 4; e++){
      int kl = koff + e*4;
      u16x4 v = *(const u16x4*)(Ubf + (size_t)(k0+kl)*UDIM + m0 + ml);
      At[(ml+0)*72 + kl] = v[0];
      At[(ml+1)*72 + kl] = v[1];
      At[(ml+2)*72 + kl] = v[2];
      At[(ml+3)*72 + kl] = v[3];
    }
    {
      const unsigned short* q = QT + (size_t)bc*BSTR + k0 + bseg*16;
      *(bf16x8*)&Bt[bc*72 + bseg*16]     = *(const bf16x8*)(q);
      *(bf16x8*)&Bt[bc*72 + bseg*16 + 8] = *(const bf16x8*)(q + 8);
    }
    __syncthreads();
    #pragma unroll
    for (int ks = 0; ks < 2; ks++){
      bf16x8 af[2], bv[2];
      #pragma unroll
      for (int t = 0; t < 2; t++){
        af[t] = *(const bf16x8*)&At[(wm + t*16 + lr)*72 + ks*32 + quad*8];
        bv[t] = *(const bf16x8*)&Bt[(wn + t*16 + lr)*72 + ks*32 + quad*8];
      }
      #pragma unroll
      for (int tm = 0; tm < 2; tm++)
        #pragma unroll
        for (int tn = 0; tn < 2; tn++)
          acc[tm][tn] = __builtin_amdgcn_mfma_f32_16x16x32_bf16(af[tm], bv[tn], acc[tm][tn], 0, 0, 0);
    }
    __syncthreads();
  }
  float* dst = part + (size_t)s * SLAB;
  #pragma unroll
  for (int tm = 0; tm < 2; tm++)
    #pragma unroll
    for (int tn = 0; tn < 2; tn++)
      #pragma unroll
      for (int e = 0; e < 4; e++)
        dst[(size_t)(m0 + wm + tm*16 + quad*4 + e)*64 + wn + tn*16 + lr] = acc[tm][tn][e];

  // ---- fold: last block for m0 reduces 22 slabs, scales by lmbd/64, writes G2T
  __threadfence();
  __syncthreads();
  if (tid == 0) scnt = atomicAdd(&ctr[144 + blockIdx.x], 1u);
  __syncthreads();
  if (scnt == NSU - 1){
    __threadfence();
    const float* base = part + (size_t)m0*64;
    for (int idx = tid; idx < 4096; idx += 256){
      int m = m0 + (idx >> 6), c = idx & 63;
      float v = 0.f;
      #pragma unroll
      for (int s2 = 0; s2 < NSU; s2++) v += base[s2*SLAB + idx];
      unsigned short h = 0;
      if (m < NV) h = f2bf(v * lm[m] * (1.0f/64.0f));
      G2T[(size_t)c*BSTR + m] = h;
    }
  }
}

// =============== gemmF: F = Ubf @ G2, split-K + fold -> Fbf. grid (43,22) ===
__global__ __launch_bounds__(256) void gemmF(
    const unsigned short* __restrict__ Ubf, const unsigned short* __restrict__ G2T,
    float* __restrict__ part, unsigned int* __restrict__ ctr,
    unsigned short* __restrict__ Fbf)
{
  __shared__ __align__(16) unsigned short At[64*72];
  __shared__ __align__(16) unsigned short Bt[64*72];
  __shared__ unsigned int scnt;
  const int tid = threadIdx.x;
  const int lane = tid & 63, wave = tid >> 6, quad = lane >> 4, lr = lane & 15;
  const int m0 = blockIdx.x * 64;
  const int s  = blockIdx.y;
  const int kbeg = s * 128, kend = min(kbeg + 128, UDIM);
  const int wm = (wave & 1) * 32, wn = (wave >> 1) * 32;
  const int bc = tid >> 2, bseg = tid & 3;
  const int srow = wave*8 + (lane >> 3), seg = lane & 7;
  f32x4 acc[2][2] = {};

  for (int k0 = kbeg; k0 < kend; k0 += 64){
    #pragma unroll
    for (int e = 0; e < 2; e++){
      int row = e*32 + srow;
      bf16x8 ua = *(const bf16x8*)(Ubf + (size_t)(m0+row)*UDIM + k0 + seg*8);
      *(bf16x8*)&At[row*72 + seg*8] = ua;
    }
    {
      const unsigned short* g = G2T + (size_t)bc*BSTR + k0 + bseg*16;
      *(bf16x8*)&Bt[bc*72 + bseg*16]     = *(const bf16x8*)(g);
      *(bf16x8*)&Bt[bc*72 + bseg*16 + 8] = *(const bf16x8*)(g + 8);
    }
    __syncthreads();
    #pragma unroll
    for (int ks = 0; ks < 2; ks++){
      bf16x8 af[2], bv[2];
      #pragma unroll
      for (int t = 0; t < 2; t++){
        af[t] = *(const bf16x8*)&At[(wm + t*16 + lr)*72 + ks*32 + quad*8];
        bv[t] = *(const bf16x8*)&Bt[(wn + t*16 + lr)*72 + ks*32 + quad*8];
      }
      #pragma unroll
      for (int tm = 0; tm < 2; tm++)
        #pragma unroll
        for (int tn = 0; tn < 2; tn++)
          acc[tm][tn] = __builtin_amdgcn_mfma_f32_16x16x32_bf16(af[tm], bv[ks == 0 ? tn : tn], acc[tm][tn], 0, 0, 0);
    }
    __syncthreads();
  }
  float* dst = part + (size_t)s * SLAB;
  #pragma unroll
  for (int tm = 0; tm < 2; tm++)
    #pragma unroll
    for (int tn = 0; tn < 2; tn++)
      #pragma unroll
      for (int e = 0; e < 4; e++)
        dst[(size_t)(m0 + wm + tm*16 + quad*4 + e)*64 + wn + tn*16 + lr] = acc[tm][tn][e];

  // ---- fold: last block for m0 reduces 22 slabs -> Fbf row-major bf16
  __threadfence();
  __syncthreads();
  if (tid == 0) scnt = atomicAdd(&ctr[192 + blockIdx.x], 1u);
  __syncthreads();
  if (scnt == NSU - 1){
    __threadfence();
    const float* base = part + (size_t)m0*64;
    for (int idx = tid; idx < 4096; idx += 256){
      int m = m0 + (idx >> 6), c = idx & 63;
      float v = 0.f;
      #pragma unroll
      for (int s2 = 0; s2 < NSU; s2++) v += base[s2*SLAB + idx];
      Fbf[(size_t)m*64 + c] = (m < NV) ? f2bf(v) : (unsigned short)0;
    }
  }
}

// ====== fused: |F K^T| -> masked exp + row-sum -> P V =======================
// 16 rows/block, 512 threads (8 waves), 170 blocks (<=1 block/CU).
// Phase A: 8 waves split 170 K-tiles; 16x16 MFMA holds 16 DISTINCT rows.
// Phase C: wave pairs split the 85 kt-tiles; LDS combine.
__global__ __launch_bounds__(512) void fused_attn(
    const unsigned short* __restrict__ Fbf, const unsigned short* __restrict__ K16f,
    const unsigned int* __restrict__ Abits, const unsigned short* __restrict__ VTf,
    float* __restrict__ Hout)
{
  __shared__ __align__(16) unsigned short pbuf[16*PSTR];   // 87.3 KB
  __shared__ unsigned int mrow[16*MWPR];                   // 5.6 KB
  __shared__ float swave[8][16];
  __shared__ float rinv[16];
  __shared__ __align__(16) float obuf[4][256];             // 4 KB
  const int tid  = threadIdx.x;
  const int lane = tid & 63, wave = tid >> 6;
  const int quad = lane >> 4, lr = lane & 15;
  const int i0 = blockIdx.x * 16;

  for (int idx = tid; idx < 16*MWPR; idx += 512){
    int r = idx / MWPR;
    unsigned int v = 0;
    if (i0 + r < NV) v = Abits[(size_t)(i0 + r)*MWPR + (idx - r*MWPR)];
    mrow[idx] = v;
  }
  // F fragments straight from Fbf (L2-hot, 16 distinct rows per wave)
  const bf16x8 af0 = *(const bf16x8*)(Fbf + (size_t)(i0 + lr)*64 + quad*8);
  const bf16x8 af1 = *(const bf16x8*)(Fbf + (size_t)(i0 + lr)*64 + 32 + quad*8);
  __syncthreads();

  float psum[4] = {0.f, 0.f, 0.f, 0.f};
  {
    int t = wave;
    const unsigned short* kb = K16f + t*1024 + lr*32 + quad*8;
    bf16x8 b0 = *(const bf16x8*)(kb);
    bf16x8 b1 = *(const bf16x8*)(kb + 512);
    while (t < 170){
      int tn = t + 8;
      bf16x8 n0 = b0, n1 = b1;
      if (tn < 170){
        const unsigned short* nb = K16f + tn*1024 + lr*32 + quad*8;
        n0 = *(const bf16x8*)(nb);
        n1 = *(const bf16x8*)(nb + 512);
      }
      f32x4 sv0 = {}, sv1 = {};
      sv0 = __builtin_amdgcn_mfma_f32_16x16x32_bf16(af0, b0, sv0, 0, 0, 0);
      sv1 = __builtin_amdgcn_mfma_f32_16x16x32_bf16(af1, b1, sv1, 0, 0, 0);
      f32x4 sv = sv0 + sv1;
      {
        int col = t*16 + lr;                 // C: col=lr -> K-row, row=quad*4+e -> F-row
        int ss = col & 255, ll = ss >> 2;
        int wsh = (col >> 8)*8 + (ss & 3)*2 + (ll >> 5);
        int bit = ll & 31;
        #pragma unroll
        for (int e = 0; e < 4; e++){
          int r = quad*4 + e;
          float p = 0.f;
          if ((mrow[r*MWPR + wsh] >> bit) & 1u) p = __expf(fabsf(sv[e]));
          psum[e] += p;
          pbuf[r*PSTR + col] = f2bf(p);
        }
      }
      b0 = n0; b1 = n1; t = tn;
    }
  }
  #pragma unroll
  for (int e = 0; e < 4; e++){
    float v = psum[e];
    #pragma unroll
    for (int o = 1; o <= 8; o <<= 1) v += __shfl_xor(v, o, 64);
    if (lr == 0) swave[wave][quad*4 + e] = v;
  }
  __syncthreads();
  if (tid < 16){
    float s = 0.f;
    #pragma unroll
    for (int w = 0; w < 8; w++) s += swave[w][tid];
    rinv[tid] = (s > 0.f) ? (1.f/s) : 0.f;
  }
  __syncthreads();

  // Phase C: O = P @ V. wave&3 -> col group, wave>>2 -> kt half.
  const int c0 = (wave & 3) * 16;
  const int ktbeg = (wave >> 2) ? 43 : 0;
  const int ktend = (wave >> 2) ? 85 : 43;
  f32x4 acc = {};
  {
    bf16x8 bv = *(const bf16x8*)&VTf[ktbeg*2048 + (c0 + lr)*32 + quad*8];
    for (int kt = ktbeg; kt < ktend; kt++){
      bf16x8 bn = bv;
      if (kt + 1 < ktend) bn = *(const bf16x8*)&VTf[(kt+1)*2048 + (c0 + lr)*32 + quad*8];
      bf16x8 af = *(const bf16x8*)&pbuf[lr*PSTR + kt*32 + quad*8];
      acc = __builtin_amdgcn_mfma_f32_16x16x32_bf16(af, bv, acc, 0, 0, 0);
      bv = bn;
    }
  }
  if (wave >= 4) *(f32x4*)&obuf[wave & 3][lane*4] = acc;
  __syncthreads();
  if (wave < 4){
    f32x4 o = *(const f32x4*)&obuf[wave][lane*4];
    acc += o;
    #pragma unroll
    for (int e = 0; e < 4; e++){
      int r = quad*4 + e;
      int i = i0 + r;
      if (i < NV) Hout[(size_t)i*64 + c0 + lr] = acc[e] * rinv[r];
    }
  }
}

extern "C" void kernel_launch(void* const* d_in, const int* in_sizes, int n_in,
                              void* d_out, int out_size, void* d_ws, size_t ws_size,
                              hipStream_t stream){
  (void)in_sizes; (void)n_in; (void)out_size; (void)ws_size;
  const float* X  = (const float*)d_in[0];
  const int*   A  = (const int*)d_in[1];
  const float* U  = (const float*)d_in[2];
  const float* WK = (const float*)d_in[3];
  const float* WQ = (const float*)d_in[4];
  const float* WV = (const float*)d_in[5];
  const float* lm = (const float*)d_in[6];

  char* ws = (char*)d_ws;
  size_t off = 0;
  auto alloc = [&](size_t bytes){ size_t o = off; off = (off + bytes + 255) & ~(size_t)255; return o; };
  float*          part = (float*)(ws + alloc(24*SLAB*4));                      // 16.9 MB
  unsigned short* Ubf  = (unsigned short*)(ws + alloc((size_t)UDIM*UDIM*2));   // 15.15 MB
  unsigned short* Xbf  = (unsigned short*)(ws + alloc((size_t)UDIM*XCOLS*2));  // 8.10 MB
  unsigned short* Wbf  = (unsigned short*)(ws + alloc((size_t)192*XCOLS*2));
  unsigned short* K16f = (unsigned short*)(ws + alloc((size_t)170*1024*2));
  unsigned short* QT16 = (unsigned short*)(ws + alloc((size_t)64*BSTR*2));
  unsigned short* G2T  = (unsigned short*)(ws + alloc((size_t)64*BSTR*2));
  unsigned short* VTf  = (unsigned short*)(ws + alloc((size_t)85*2048*2));
  unsigned short* Fbf  = (unsigned short*)(ws + alloc((size_t)BSTR*64*2));
  unsigned int*   Abits= (unsigned int*)(ws + alloc((size_t)NV*MWPR*4));
  unsigned int*   ctr  = (unsigned int*)(ws + alloc(256*4));
  // total ~44 MB

  convert_all<<<dim3(8404), 256, 0, stream>>>(X, WK, WQ, WV, U, A, Xbf, Wbf, Ubf, Abits, ctr);
  proj<<<dim3(43, NSP, 3), 256, 0, stream>>>(Xbf, Wbf, part, ctr, K16f, QT16, VTf);
  gemmG<<<dim3(43, NSU), 256, 0, stream>>>(Ubf, QT16, part, ctr, lm, G2T);
  gemmF<<<dim3(43, NSU), 256, 0, stream>>>(Ubf, G2T, part, ctr, Fbf);
  fused_attn<<<dim3(170), 512, 0, stream>>>(Fbf, K16f, Abits, VTf, (float*)d_out);
}

// Round 4
// 182.149 us; speedup vs baseline: 3.5006x; 3.5006x over previous
//
#include <hip/hip_runtime.h>

#define NV 2708
#define INC 1433
#define XCOLS 1472        // padded X/W cols (23*64)
#define UDIM 2752         // padded U dims (43*64)
#define PSTR 2728         // pbuf stride in shorts: 1364 dwords, %32=20 -> ~2-way on b128 reads
#define BSTR 2752
#define SLAB ((size_t)(2752*64))   // fp32 partial slab
#define MWPR 88
#define NSP 8             // proj split-K chunks
#define NSU 22            // gemmG/gemmF split-K chunks (2752 = 21*128 + 64)

typedef __attribute__((ext_vector_type(8))) short bf16x8;
typedef __attribute__((ext_vector_type(4))) float f32x4;
typedef __attribute__((ext_vector_type(4))) unsigned short u16x4;

__device__ __forceinline__ unsigned short f2bf(float f){
  union { float f; unsigned int i; } v; v.f = f;
  return (unsigned short)((v.i + 0x7fffu + ((v.i >> 16) & 1u)) >> 16);  // RNE
}

// convert one fp32 row (INC elems, 4B-aligned base) to bf16 with zero pad to
// XCOLS. float2 via parity shift: src+sh is 8B-aligned (sh in {0,1}).
__device__ __forceinline__ void conv_row(const float* __restrict__ src,
                                         unsigned short* __restrict__ dst, int tid){
  const int sh = ((unsigned int)((size_t)src >> 2)) & 1;
  if (tid == 0){ int ce = sh ? 0 : (INC - 1); dst[ce] = f2bf(src[ce]); }
  const float2* s2 = (const float2*)(src + sh);
  for (int c2 = tid; c2 < (INC - 1)/2; c2 += 256){   // 716 pairs
    float2 v = s2[c2];
    int c = sh + c2*2;
    dst[c]     = f2bf(v.x);
    dst[c + 1] = f2bf(v.y);
  }
  for (int c = INC + tid; c < XCOLS; c += 256) dst[c] = 0;
}

// ====== convert_all: one-row blocks, short per-wave chains ==================
__global__ __launch_bounds__(256) void convert_all(
    const float* __restrict__ X, const float* __restrict__ WK,
    const float* __restrict__ WQ, const float* __restrict__ WV,
    const float* __restrict__ U, const int* __restrict__ A,
    unsigned short* __restrict__ Xbf, unsigned short* __restrict__ Wbf,
    unsigned short* __restrict__ Ubf, unsigned int* __restrict__ Abits)
{
  const int bx = blockIdx.x;
  const int tid = threadIdx.x;
  if (bx < 2752){                      // U row (16B-aligned: float4)
    const int row = bx;
    unsigned short* dst = Ubf + (size_t)row*UDIM;
    if (row < NV){
      const float* src = U + (size_t)row*NV;
      for (int c4 = tid; c4 < 688; c4 += 256){
        float4 v = make_float4(0.f,0.f,0.f,0.f);
        if (c4 < 677) v = *(const float4*)(src + c4*4);
        u16x4 h = { f2bf(v.x), f2bf(v.y), f2bf(v.z), f2bf(v.w) };
        *(u16x4*)(dst + c4*4) = h;
      }
    } else {
      u16x4 zz = {0,0,0,0};
      for (int c4 = tid; c4 < 688; c4 += 256) *(u16x4*)(dst + c4*4) = zz;
    }
  } else if (bx < 5504){               // X row (float2 parity trick)
    const int row = bx - 2752;
    unsigned short* dst = Xbf + (size_t)row*XCOLS;
    if (row < NV){
      conv_row(X + (size_t)row*INC, dst, tid);
    } else {
      u16x4 zz = {0,0,0,0};
      for (int c4 = tid; c4 < XCOLS/4; c4 += 256) *(u16x4*)(dst + c4*4) = zz;
    }
  } else if (bx < 5696){               // W row (192 rows)
    const int row = bx - 5504;
    const float* s = (row < 64) ? WK : (row < 128) ? WQ : WV;
    conv_row(s + (size_t)(row & 63)*INC, Wbf + (size_t)row*XCOLS, tid);
  } else {                             // A row -> bitmask (int4, grouped layout)
    const int i = bx - 5696;
    const int lane = tid & 63, wave = tid >> 6;
    const int* arow = A + (size_t)i*NV;
    unsigned int* drow = Abits + (size_t)i*MWPR;
    // word(col): g=col>>8, s=col&255 -> g*8+(s&3)*2+((s>>2)>>5), bit (s>>2)&31
    for (int g = wave; g < 11; g += 4){
      int base = g*256 + lane*4;
      int4 v = make_int4(0,0,0,0);
      if (base < NV) v = *(const int4*)(arow + base);   // base<=2704 -> +3 in bounds
      unsigned long long m0 = __ballot(v.x != 0);
      unsigned long long m1 = __ballot(v.y != 0);
      unsigned long long m2 = __ballot(v.z != 0);
      unsigned long long m3 = __ballot(v.w != 0);
      if (lane < 8){
        unsigned long long mm = (lane < 2) ? m0 : (lane < 4) ? m1 : (lane < 6) ? m2 : m3;
        drow[g*8 + lane] = (lane & 1) ? (unsigned int)(mm >> 32) : (unsigned int)mm;
      }
    }
  }
}

// =============== proj: partials of {K,Q,V} = Xbf @ Wbf^T. grid (43,8,3) =====
__global__ __launch_bounds__(256) void proj(
    const unsigned short* __restrict__ Xbf, const unsigned short* __restrict__ Wbf,
    float* __restrict__ part)
{
  __shared__ __align__(16) unsigned short At[64*72];
  __shared__ __align__(16) unsigned short Bt[64*72];
  const int tid = threadIdx.x;
  const int lane = tid & 63, wave = tid >> 6, quad = lane >> 4, lr = lane & 15;
  const int m0 = blockIdx.x * 64;
  const int s  = blockIdx.y, z = blockIdx.z;
  const int kbeg = s * 192, kend = min(kbeg + 192, XCOLS);  // last chunk 128
  const int wm = (wave & 1) * 32, wn = (wave >> 1) * 32;
  const unsigned short* Wz = Wbf + (size_t)z*64*XCOLS;
  const int srow = wave*8 + (lane >> 3), seg = lane & 7;
  f32x4 acc[2][2] = {};

  for (int k0 = kbeg; k0 < kend; k0 += 64){
    #pragma unroll
    for (int e = 0; e < 2; e++){
      int row = e*32 + srow;
      bf16x8 xa = *(const bf16x8*)(Xbf + (size_t)(m0+row)*XCOLS + k0 + seg*8);
      bf16x8 wb = *(const bf16x8*)(Wz  + (size_t)row*XCOLS      + k0 + seg*8);
      *(bf16x8*)&At[row*72 + seg*8] = xa;
      *(bf16x8*)&Bt[row*72 + seg*8] = wb;
    }
    __syncthreads();
    #pragma unroll
    for (int ks = 0; ks < 2; ks++){
      bf16x8 af[2], bv[2];
      #pragma unroll
      for (int t = 0; t < 2; t++){
        af[t] = *(const bf16x8*)&At[(wm + t*16 + lr)*72 + ks*32 + quad*8];
        bv[t] = *(const bf16x8*)&Bt[(wn + t*16 + lr)*72 + ks*32 + quad*8];
      }
      #pragma unroll
      for (int tm = 0; tm < 2; tm++)
        #pragma unroll
        for (int tn = 0; tn < 2; tn++)
          acc[tm][tn] = __builtin_amdgcn_mfma_f32_16x16x32_bf16(af[tm], bv[tn], acc[tm][tn], 0, 0, 0);
    }
    __syncthreads();
  }
  float* dst = part + (size_t)(z*NSP + s) * SLAB;
  #pragma unroll
  for (int tm = 0; tm < 2; tm++)
    #pragma unroll
    for (int tn = 0; tn < 2; tn++)
      #pragma unroll
      for (int e = 0; e < 4; e++)
        dst[(size_t)(m0 + wm + tm*16 + quad*4 + e)*64 + wn + tn*16 + lr] = acc[tm][tn][e];
}

// K16f frag-linear ; QT16 [c][m] ; VTf frag-linear. grid (688, 3).
__global__ __launch_bounds__(256) void reduce_proj(
    const float* __restrict__ part, unsigned short* __restrict__ K16f,
    unsigned short* __restrict__ QT16, unsigned short* __restrict__ VTf)
{
  int idx = blockIdx.x*256 + threadIdx.x;       // < 2752*64
  int z = blockIdx.y;
  int m = idx >> 6, c = idx & 63;
  const float* base = part + (size_t)z*NSP*SLAB + idx;
  float v = 0.f;
  #pragma unroll
  for (int s = 0; s < NSP; s++) v += base[s*SLAB];
  unsigned short h = (m < NV) ? f2bf(v) : (unsigned short)0;
  if (z == 0){
    if (m < 2720) K16f[((m>>4)*2 + (c>>5))*512 + (m&15)*32 + (c&31)] = h;
  } else if (z == 1){
    QT16[(size_t)c*BSTR + m] = h;
  } else {
    if (m < 2720) VTf[(m>>5)*2048 + c*32 + (m&31)] = h;
  }
}

// =============== gemmG: partials of G = Ubf^T @ Q. grid (43,22) =============
__global__ __launch_bounds__(256) void gemmG(
    const unsigned short* __restrict__ Ubf, const unsigned short* __restrict__ QT,
    float* __restrict__ part)
{
  __shared__ __align__(16) unsigned short At[64*72];
  __shared__ __align__(16) unsigned short Bt[64*72];
  const int tid = threadIdx.x;
  const int lane = tid & 63, wave = tid >> 6, quad = lane >> 4, lr = lane & 15;
  const int m0 = blockIdx.x * 64;
  const int s  = blockIdx.y;
  const int kbeg = s * 128, kend = min(kbeg + 128, UDIM);   // last chunk 64
  const int wm = (wave & 1) * 32, wn = (wave >> 1) * 32;
  const int bc = tid >> 2, bseg = tid & 3;
  const int ml = (lane & 15)*4, koff = wave*16 + (lane >> 4);
  f32x4 acc[2][2] = {};

  for (int k0 = kbeg; k0 < kend; k0 += 64){
    #pragma unroll
    for (int e = 0; e < 4; e++){
      int kl = koff + e*4;
      u16x4 v = *(const u16x4*)(Ubf + (size_t)(k0+kl)*UDIM + m0 + ml);
      At[(ml+0)*72 + kl] = v[0];
      At[(ml+1)*72 + kl] = v[1];
      At[(ml+2)*72 + kl] = v[2];
      At[(ml+3)*72 + kl] = v[3];
    }
    {
      const unsigned short* q = QT + (size_t)bc*BSTR + k0 + bseg*16;
      *(bf16x8*)&Bt[bc*72 + bseg*16]     = *(const bf16x8*)(q);
      *(bf16x8*)&Bt[bc*72 + bseg*16 + 8] = *(const bf16x8*)(q + 8);
    }
    __syncthreads();
    #pragma unroll
    for (int ks = 0; ks < 2; ks++){
      bf16x8 af[2], bv[2];
      #pragma unroll
      for (int t = 0; t < 2; t++){
        af[t] = *(const bf16x8*)&At[(wm + t*16 + lr)*72 + ks*32 + quad*8];
        bv[t] = *(const bf16x8*)&Bt[(wn + t*16 + lr)*72 + ks*32 + quad*8];
      }
      #pragma unroll
      for (int tm = 0; tm < 2; tm++)
        #pragma unroll
        for (int tn = 0; tn < 2; tn++)
          acc[tm][tn] = __builtin_amdgcn_mfma_f32_16x16x32_bf16(af[tm], bv[tn], acc[tm][tn], 0, 0, 0);
    }
    __syncthreads();
  }
  float* dst = part + (size_t)s * SLAB;
  #pragma unroll
  for (int tm = 0; tm < 2; tm++)
    #pragma unroll
    for (int tn = 0; tn < 2; tn++)
      #pragma unroll
      for (int e = 0; e < 4; e++)
        dst[(size_t)(m0 + wm + tm*16 + quad*4 + e)*64 + wn + tn*16 + lr] = acc[tm][tn][e];
}

// G2T16[c][m] = bf16(G[m][c] * lmbd[m]/64), zero pads. grid 688.
__global__ __launch_bounds__(256) void reduce_g(
    const float* __restrict__ part, const float* __restrict__ lm,
    unsigned short* __restrict__ G2T)
{
  int idx = blockIdx.x*256 + threadIdx.x;
  int m = idx >> 6, c = idx & 63;
  const float* base = part + idx;
  float v = 0.f;
  #pragma unroll
  for (int s = 0; s < NSU; s++) v += base[s*SLAB];
  unsigned short h = 0;
  if (m < NV) h = f2bf(v * lm[m] * (1.0f/64.0f));
  G2T[(size_t)c*BSTR + m] = h;
}

// =============== gemmF: partials of F = Ubf @ G2. grid (43,22) ==============
__global__ __launch_bounds__(256) void gemmF(
    const unsigned short* __restrict__ Ubf, const unsigned short* __restrict__ G2T,
    float* __restrict__ part)
{
  __shared__ __align__(16) unsigned short At[64*72];
  __shared__ __align__(16) unsigned short Bt[64*72];
  const int tid = threadIdx.x;
  const int lane = tid & 63, wave = tid >> 6, quad = lane >> 4, lr = lane & 15;
  const int m0 = blockIdx.x * 64;
  const int s  = blockIdx.y;
  const int kbeg = s * 128, kend = min(kbeg + 128, UDIM);
  const int wm = (wave & 1) * 32, wn = (wave >> 1) * 32;
  const int bc = tid >> 2, bseg = tid & 3;
  const int srow = wave*8 + (lane >> 3), seg = lane & 7;
  f32x4 acc[2][2] = {};

  for (int k0 = kbeg; k0 < kend; k0 += 64){
    #pragma unroll
    for (int e = 0; e < 2; e++){
      int row = e*32 + srow;
      bf16x8 ua = *(const bf16x8*)(Ubf + (size_t)(m0+row)*UDIM + k0 + seg*8);
      *(bf16x8*)&At[row*72 + seg*8] = ua;
    }
    {
      const unsigned short* g = G2T + (size_t)bc*BSTR + k0 + bseg*16;
      *(bf16x8*)&Bt[bc*72 + bseg*16]     = *(const bf16x8*)(g);
      *(bf16x8*)&Bt[bc*72 + bseg*16 + 8] = *(const bf16x8*)(g + 8);
    }
    __syncthreads();
    #pragma unroll
    for (int ks = 0; ks < 2; ks++){
      bf16x8 af[2], bv[2];
      #pragma unroll
      for (int t = 0; t < 2; t++){
        af[t] = *(const bf16x8*)&At[(wm + t*16 + lr)*72 + ks*32 + quad*8];
        bv[t] = *(const bf16x8*)&Bt[(wn + t*16 + lr)*72 + ks*32 + quad*8];
      }
      #pragma unroll
      for (int tm = 0; tm < 2; tm++)
        #pragma unroll
        for (int tn = 0; tn < 2; tn++)
          acc[tm][tn] = __builtin_amdgcn_mfma_f32_16x16x32_bf16(af[tm], bv[tn], acc[tm][tn], 0, 0, 0);
    }
    __syncthreads();
  }
  float* dst = part + (size_t)s * SLAB;
  #pragma unroll
  for (int tm = 0; tm < 2; tm++)
    #pragma unroll
    for (int tn = 0; tn < 2; tn++)
      #pragma unroll
      for (int e = 0; e < 4; e++)
        dst[(size_t)(m0 + wm + tm*16 + quad*4 + e)*64 + wn + tn*16 + lr] = acc[tm][tn][e];
}

// ====== fused: reduce-F + |F K^T| -> masked exp + row-sum -> P V ============
// 16 rows/block, 512 threads (8 waves), 170 blocks (1 block/CU, no tail).
// Phase A: 8 waves split 170 K-tiles; 16x16 MFMA holds 16 DISTINCT rows.
// Phase C: wave pairs split the 85 kt-tiles; LDS combine.
__global__ __launch_bounds__(512) void fused_attn(
    const float* __restrict__ partF, const unsigned short* __restrict__ K16f,
    const unsigned int* __restrict__ Abits, const unsigned short* __restrict__ VTf,
    float* __restrict__ Hout)
{
  __shared__ __align__(16) unsigned short pbuf[16*PSTR];   // 87.3 KB
  __shared__ __align__(16) unsigned short fbuf[16*64];     // 2 KB
  __shared__ unsigned int mrow[16*MWPR];                   // 5.6 KB
  __shared__ float swave[8][16];
  __shared__ float rinv[16];
  __shared__ __align__(16) float obuf[4][256];             // 4 KB
  const int tid  = threadIdx.x;
  const int lane = tid & 63, wave = tid >> 6;
  const int quad = lane >> 4, lr = lane & 15;
  const int i0 = blockIdx.x * 16;

  // stage F rows (sum 22 slabs; rows >= NV are zero in part)
  #pragma unroll
  for (int h = 0; h < 2; h++){
    int idx = h*512 + tid;              // < 1024
    const float* base = partF + (size_t)(i0 + (idx >> 6))*64 + (idx & 63);
    float v = 0.f;
    #pragma unroll
    for (int s = 0; s < NSU; s++) v += base[s*SLAB];
    fbuf[idx] = f2bf(v);
  }
  for (int idx = tid; idx < 16*MWPR; idx += 512){
    int r = idx / MWPR;
    unsigned int v = 0;
    if (i0 + r < NV) v = Abits[(size_t)(i0 + r)*MWPR + (idx - r*MWPR)];
    mrow[idx] = v;
  }
  __syncthreads();

  // A-fragment: 16 distinct F rows (row = lr, k = quad*8 + j [+32 for af1])
  const bf16x8 af0 = *(const bf16x8*)&fbuf[lr*64 + quad*8];
  const bf16x8 af1 = *(const bf16x8*)&fbuf[lr*64 + 32 + quad*8];
  float psum[4] = {0.f, 0.f, 0.f, 0.f};
  {
    int t = wave;
    const unsigned short* kb = K16f + t*1024 + lr*32 + quad*8;
    bf16x8 b0 = *(const bf16x8*)(kb);
    bf16x8 b1 = *(const bf16x8*)(kb + 512);
    while (t < 170){
      int tn = t + 8;
      bf16x8 n0 = b0, n1 = b1;
      if (tn < 170){
        const unsigned short* nb = K16f + tn*1024 + lr*32 + quad*8;
        n0 = *(const bf16x8*)(nb);
        n1 = *(const bf16x8*)(nb + 512);
      }
      f32x4 sv0 = {}, sv1 = {};
      sv0 = __builtin_amdgcn_mfma_f32_16x16x32_bf16(af0, b0, sv0, 0, 0, 0);
      sv1 = __builtin_amdgcn_mfma_f32_16x16x32_bf16(af1, b1, sv1, 0, 0, 0);
      f32x4 sv = sv0 + sv1;
      {
        int col = t*16 + lr;                 // C: col=lr -> K-row, row=quad*4+e -> F-row
        int ss = col & 255, ll = ss >> 2;
        int wsh = (col >> 8)*8 + (ss & 3)*2 + (ll >> 5);
        int bit = ll & 31;
        #pragma unroll
        for (int e = 0; e < 4; e++){
          int r = quad*4 + e;
          float p = 0.f;
          if ((mrow[r*MWPR + wsh] >> bit) & 1u) p = __expf(fabsf(sv[e]));
          psum[e] += p;
          pbuf[r*PSTR + col] = f2bf(p);
        }
      }
      b0 = n0; b1 = n1; t = tn;
    }
  }
  #pragma unroll
  for (int e = 0; e < 4; e++){
    float v = psum[e];
    #pragma unroll
    for (int o = 1; o <= 8; o <<= 1) v += __shfl_xor(v, o, 64);
    if (lr == 0) swave[wave][quad*4 + e] = v;
  }
  __syncthreads();
  if (tid < 16){
    float s = 0.f;
    #pragma unroll
    for (int w = 0; w < 8; w++) s += swave[w][tid];
    rinv[tid] = (s > 0.f) ? (1.f/s) : 0.f;
  }
  __syncthreads();

  // Phase C: O = P @ V. wave&3 -> col group, wave>>2 -> kt half.
  const int c0 = (wave & 3) * 16;
  const int ktbeg = (wave >> 2) ? 43 : 0;
  const int ktend = (wave >> 2) ? 85 : 43;
  f32x4 acc = {};
  {
    bf16x8 bv = *(const bf16x8*)&VTf[ktbeg*2048 + (c0 + lr)*32 + quad*8];
    for (int kt = ktbeg; kt < ktend; kt++){
      bf16x8 bn = bv;
      if (kt + 1 < ktend) bn = *(const bf16x8*)&VTf[(kt+1)*2048 + (c0 + lr)*32 + quad*8];
      bf16x8 af = *(const bf16x8*)&pbuf[lr*PSTR + kt*32 + quad*8];
      acc = __builtin_amdgcn_mfma_f32_16x16x32_bf16(af, bv, acc, 0, 0, 0);
      bv = bn;
    }
  }
  if (wave >= 4) *(f32x4*)&obuf[wave & 3][lane*4] = acc;
  __syncthreads();
  if (wave < 4){
    f32x4 o = *(const f32x4*)&obuf[wave][lane*4];
    acc += o;
    #pragma unroll
    for (int e = 0; e < 4; e++){
      int r = quad*4 + e;
      int i = i0 + r;
      if (i < NV) Hout[(size_t)i*64 + c0 + lr] = acc[e] * rinv[r];
    }
  }
}

extern "C" void kernel_launch(void* const* d_in, const int* in_sizes, int n_in,
                              void* d_out, int out_size, void* d_ws, size_t ws_size,
                              hipStream_t stream){
  (void)in_sizes; (void)n_in; (void)out_size; (void)ws_size;
  const float* X  = (const float*)d_in[0];
  const int*   A  = (const int*)d_in[1];
  const float* U  = (const float*)d_in[2];
  const float* WK = (const float*)d_in[3];
  const float* WQ = (const float*)d_in[4];
  const float* WV = (const float*)d_in[5];
  const float* lm = (const float*)d_in[6];

  char* ws = (char*)d_ws;
  size_t off = 0;
  auto alloc = [&](size_t bytes){ size_t o = off; off = (off + bytes + 255) & ~(size_t)255; return o; };
  float*          part = (float*)(ws + alloc(24*SLAB*4));                      // 16.9 MB
  unsigned short* Ubf  = (unsigned short*)(ws + alloc((size_t)UDIM*UDIM*2));   // 15.15 MB
  unsigned short* Xbf  = (unsigned short*)(ws + alloc((size_t)UDIM*XCOLS*2));  // 8.10 MB
  unsigned short* Wbf  = (unsigned short*)(ws + alloc((size_t)192*XCOLS*2));
  unsigned short* K16f = (unsigned short*)(ws + alloc((size_t)170*1024*2));
  unsigned short* QT16 = (unsigned short*)(ws + alloc((size_t)64*BSTR*2));
  unsigned short* G2T  = (unsigned short*)(ws + alloc((size_t)64*BSTR*2));
  unsigned short* VTf  = (unsigned short*)(ws + alloc((size_t)85*2048*2));
  unsigned int*   Abits= (unsigned int*)(ws + alloc((size_t)NV*MWPR*4));
  // total ~43 MB

  convert_all<<<dim3(8404), 256, 0, stream>>>(X, WK, WQ, WV, U, A, Xbf, Wbf, Ubf, Abits);
  proj<<<dim3(43, NSP, 3), 256, 0, stream>>>(Xbf, Wbf, part);
  reduce_proj<<<dim3(688, 3), 256, 0, stream>>>(part, K16f, QT16, VTf);
  gemmG<<<dim3(43, NSU), 256, 0, stream>>>(Ubf, QT16, part);
  reduce_g<<<dim3(688), 256, 0, stream>>>(part, lm, G2T);
  gemmF<<<dim3(43, NSU), 256, 0, stream>>>(Ubf, G2T, part);
  fused_attn<<<dim3(170), 512, 0, stream>>>(part, K16f, Abits, VTf, (float*)d_out);
}